// Round 1
// baseline (2092.395 us; speedup 1.0000x reference)
//
#include <hip/hip_runtime.h>
#include <hip/hip_bf16.h>
#include <cstdint>

#define NUM_USERS 100000
#define NUM_PRODUCTS 50000
#define N_NODES 150000
#define NUM_EDGES 250000
#define D 256

// ---------------------------------------------------------------------------
// Degree / CSR construction
// ---------------------------------------------------------------------------
__global__ __launch_bounds__(256) void count_deg(const int* __restrict__ ei, int* __restrict__ cnt, int E) {
    int e = blockIdx.x * 256 + threadIdx.x;
    if (e < E) {
        atomicAdd(&cnt[ei[e]], 1);         // user endpoint
        atomicAdd(&cnt[ei[E + e]], 1);     // product endpoint (global id)
    }
}

__global__ __launch_bounds__(256) void compute_dinv(const int* __restrict__ cnt, float* __restrict__ dinv, int N) {
    int n = blockIdx.x * 256 + threadIdx.x;
    if (n < N) dinv[n] = rsqrtf((float)(cnt[n] + 1));   // +1 self loop, always >=1
}

#define SCAN_CHUNK 1024

__global__ __launch_bounds__(256) void scan_partials(const int* __restrict__ cnt, int* __restrict__ bsum, int N) {
    __shared__ int sdata[256];
    int base = blockIdx.x * SCAN_CHUNK;
    int t = threadIdx.x;
    int s = 0;
#pragma unroll
    for (int i = 0; i < 4; i++) {
        int idx = base + t * 4 + i;
        if (idx < N) s += cnt[idx];
    }
    sdata[t] = s;
    __syncthreads();
    for (int off = 128; off > 0; off >>= 1) {
        if (t < off) sdata[t] += sdata[t + off];
        __syncthreads();
    }
    if (t == 0) bsum[blockIdx.x] = sdata[0];
}

__global__ __launch_bounds__(256) void scan_bsums(const int* __restrict__ bsum, int* __restrict__ bscan,
                                                  int NB, int* __restrict__ offs, int N) {
    __shared__ int s[256];
    int t = threadIdx.x;
    int v = (t < NB) ? bsum[t] : 0;
    s[t] = v;
    __syncthreads();
    for (int off = 1; off < 256; off <<= 1) {
        int x = (t >= off) ? s[t - off] : 0;
        __syncthreads();
        s[t] += x;
        __syncthreads();
    }
    if (t < NB) bscan[t] = s[t] - v;      // exclusive
    if (t == 255) offs[N] = s[255];       // total (= 2*E)
}

__global__ __launch_bounds__(256) void scan_final(const int* __restrict__ cnt, const int* __restrict__ bscan,
                                                  int* __restrict__ offs, int N) {
    __shared__ int sdata[256];
    int base = blockIdx.x * SCAN_CHUNK;
    int t = threadIdx.x;
    int v[4];
    int loc = 0;
#pragma unroll
    for (int i = 0; i < 4; i++) {
        int idx = base + t * 4 + i;
        v[i] = (idx < N) ? cnt[idx] : 0;
        loc += v[i];
    }
    int mine = loc;
    sdata[t] = loc;
    __syncthreads();
    for (int off = 1; off < 256; off <<= 1) {
        int x = (t >= off) ? sdata[t - off] : 0;
        __syncthreads();
        sdata[t] += x;
        __syncthreads();
    }
    int pre = sdata[t] - mine + bscan[blockIdx.x];
#pragma unroll
    for (int i = 0; i < 4; i++) {
        int idx = base + t * 4 + i;
        if (idx < N) offs[idx] = pre;
        pre += v[i];
    }
}

__global__ __launch_bounds__(256) void fill_adj(const int* __restrict__ ei, const int* __restrict__ offs,
                                                int* __restrict__ cursor, int* __restrict__ adj, int E) {
    int e = blockIdx.x * 256 + threadIdx.x;
    if (e >= E) return;
    int u = ei[e];
    int p = ei[E + e];
    int pos = atomicAdd(&cursor[u], 1);
    adj[offs[u] + pos] = p;
    pos = atomicAdd(&cursor[p], 1);
    adj[offs[p] + pos] = u;
}

// ---------------------------------------------------------------------------
// Row-tile GEMM: out[out_base+row] = (in[row] @ W) (+bias) (+addv[row]) (*scale[row])
// 16 rows per block, 256 threads (thread = output column), K in {128,256}.
// ---------------------------------------------------------------------------
template <int K>
__global__ __launch_bounds__(256) void gemm_rows(
    const float* __restrict__ in,      // [nrows, K]
    const float* __restrict__ W,       // [K, 256]
    const float* __restrict__ bias,    // [256] or null
    const float* __restrict__ addv,    // [nrows, 256] or null
    const float* __restrict__ scale,   // per-row scale or null
    float* __restrict__ out,           // rows at out_base
    int out_base) {
    __shared__ float sIn[16 * K];
    const int row0 = blockIdx.x * 16;
    const int t = threadIdx.x;

    const float4* src = (const float4*)(in + (size_t)row0 * K);
    float4* dst = (float4*)sIn;
#pragma unroll
    for (int i = 0; i < K / 64; i++) dst[t + i * 256] = src[t + i * 256];
    __syncthreads();

    const int col = t;
    float acc[16];
#pragma unroll
    for (int r = 0; r < 16; r++) acc[r] = 0.f;

    for (int k = 0; k < K; k += 4) {
        float w0 = W[(k + 0) * 256 + col];
        float w1 = W[(k + 1) * 256 + col];
        float w2 = W[(k + 2) * 256 + col];
        float w3 = W[(k + 3) * 256 + col];
#pragma unroll
        for (int r = 0; r < 16; r++) {
            float4 xv = *(const float4*)&sIn[r * K + k];
            acc[r] = fmaf(xv.x, w0, acc[r]);
            acc[r] = fmaf(xv.y, w1, acc[r]);
            acc[r] = fmaf(xv.z, w2, acc[r]);
            acc[r] = fmaf(xv.w, w3, acc[r]);
        }
    }

    float b = bias ? bias[col] : 0.f;
#pragma unroll
    for (int r = 0; r < 16; r++) {
        int row = row0 + r;
        float v = acc[r] + b;
        if (addv) v += addv[(size_t)row * D + col];
        if (scale) v *= scale[row];
        out[(size_t)(out_base + row) * D + col] = v;
    }
}

// ---------------------------------------------------------------------------
// GCN aggregation: out[d] = dinv[d] * (g[d] + sum_{s in adj[d]} g[s]) + bias, opt relu
// one node per block, thread = column
// ---------------------------------------------------------------------------
__global__ __launch_bounds__(256) void gcn_aggregate(
    const float* __restrict__ g, const int* __restrict__ offs, const int* __restrict__ adj,
    const float* __restrict__ dinv, const float* __restrict__ bias,
    float* __restrict__ out, int do_relu) {
    int d = blockIdx.x;
    int col = threadIdx.x;
    float a = g[(size_t)d * D + col];
    int beg = offs[d], end = offs[d + 1];
    for (int i = beg; i < end; ++i) {
        int s = adj[i];
        a += g[(size_t)s * D + col];
    }
    float v = fmaf(dinv[d], a, bias[col]);
    if (do_relu) v = fmaxf(v, 0.f);
    out[(size_t)d * D + col] = v;
}

// ---------------------------------------------------------------------------
// Edge MLP: preds[e] = relu(A[u] + B[p] + m1b) . m2w + m2b   (one wave per edge)
// ---------------------------------------------------------------------------
__global__ __launch_bounds__(256) void edge_mlp(
    const float* __restrict__ ab, const int* __restrict__ ei,
    const float* __restrict__ m1b, const float* __restrict__ m2w, const float* __restrict__ m2b,
    float* __restrict__ preds, int E) {
    int wave = threadIdx.x >> 6;
    int lane = threadIdx.x & 63;
    int e = blockIdx.x * 4 + wave;
    if (e >= E) return;
    int u = ei[e];
    int p = ei[E + e];   // global node id (>= NUM_USERS), ab row directly
    int c0 = lane * 4;
    float4 au = *(const float4*)&ab[(size_t)u * D + c0];
    float4 bp = *(const float4*)&ab[(size_t)p * D + c0];
    float4 bb = *(const float4*)&m1b[c0];
    float4 w = *(const float4*)&m2w[c0];
    float h0 = fmaxf(au.x + bp.x + bb.x, 0.f);
    float h1 = fmaxf(au.y + bp.y + bb.y, 0.f);
    float h2 = fmaxf(au.z + bp.z + bb.z, 0.f);
    float h3 = fmaxf(au.w + bp.w + bb.w, 0.f);
    float partial = h0 * w.x + h1 * w.y + h2 * w.z + h3 * w.w;
#pragma unroll
    for (int off = 32; off > 0; off >>= 1) partial += __shfl_down(partial, off);
    if (lane == 0) preds[e] = partial + m2b[0];
}

// ---------------------------------------------------------------------------
extern "C" void kernel_launch(void* const* d_in, const int* in_sizes, int n_in,
                              void* d_out, int out_size, void* d_ws, size_t ws_size,
                              hipStream_t stream) {
    const int* ei = (const int*)d_in[0];
    const float* user_feat = (const float*)d_in[1];
    const float* prod_feat = (const float*)d_in[2];
    const float* user_emb = (const float*)d_in[3];
    const float* prod_emb = (const float*)d_in[4];
    const float* uW = (const float*)d_in[5];
    const float* ub = (const float*)d_in[6];
    const float* pW = (const float*)d_in[7];
    const float* pb = (const float*)d_in[8];
    const float* c1W = (const float*)d_in[9];
    const float* c1b = (const float*)d_in[10];
    const float* c2W = (const float*)d_in[11];
    const float* c2b = (const float*)d_in[12];
    const float* m1W = (const float*)d_in[13];
    const float* m1b = (const float*)d_in[14];
    const float* m2w = (const float*)d_in[15];
    const float* m2b = (const float*)d_in[16];
    float* preds = (float*)d_out;

    // workspace layout (~312 MB)
    uint8_t* ws = (uint8_t*)d_ws;
    size_t off = 0;
    auto alloc = [&](size_t bytes) {
        size_t o = off;
        off = (off + bytes + 255) & ~(size_t)255;
        return o;
    };
    float* x = (float*)(ws + alloc((size_t)N_NODES * D * 4));
    float* g = (float*)(ws + alloc((size_t)N_NODES * D * 4));   // also A/B buffer
    float* dinv = (float*)(ws + alloc((size_t)N_NODES * 4));
    int* cnt = (int*)(ws + alloc((size_t)N_NODES * 4));
    int* cursor = (int*)(ws + alloc((size_t)N_NODES * 4));
    int* offs = (int*)(ws + alloc((size_t)(N_NODES + 1) * 4));
    int* adj = (int*)(ws + alloc((size_t)2 * NUM_EDGES * 4));
    int* bsum = (int*)(ws + alloc(4096));
    int* bscan = (int*)(ws + alloc(4096));

    const int NB = (N_NODES + SCAN_CHUNK - 1) / SCAN_CHUNK;   // 147

    hipMemsetAsync(cnt, 0, (size_t)N_NODES * 4, stream);
    hipMemsetAsync(cursor, 0, (size_t)N_NODES * 4, stream);

    // degree + CSR
    count_deg<<<(NUM_EDGES + 255) / 256, 256, 0, stream>>>(ei, cnt, NUM_EDGES);
    compute_dinv<<<(N_NODES + 255) / 256, 256, 0, stream>>>(cnt, dinv, N_NODES);
    scan_partials<<<NB, 256, 0, stream>>>(cnt, bsum, N_NODES);
    scan_bsums<<<1, 256, 0, stream>>>(bsum, bscan, NB, offs, N_NODES);
    scan_final<<<NB, 256, 0, stream>>>(cnt, bscan, offs, N_NODES);
    fill_adj<<<(NUM_EDGES + 255) / 256, 256, 0, stream>>>(ei, offs, cursor, adj, NUM_EDGES);

    // input transforms: x = feat @ W + b + emb
    gemm_rows<128><<<NUM_USERS / 16, 256, 0, stream>>>(user_feat, uW, ub, user_emb, nullptr, x, 0);
    gemm_rows<128><<<NUM_PRODUCTS / 16, 256, 0, stream>>>(prod_feat, pW, pb, prod_emb, nullptr, x, NUM_USERS);

    // conv1: g = (x @ c1W) * dinv ; x = relu(dinv*(g[d]+sum g[s]) + c1b)
    gemm_rows<256><<<N_NODES / 16, 256, 0, stream>>>(x, c1W, nullptr, nullptr, dinv, g, 0);
    gcn_aggregate<<<N_NODES, 256, 0, stream>>>(g, offs, adj, dinv, c1b, x, 1);

    // conv2
    gemm_rows<256><<<N_NODES / 16, 256, 0, stream>>>(x, c2W, nullptr, nullptr, dinv, g, 0);
    gcn_aggregate<<<N_NODES, 256, 0, stream>>>(g, offs, adj, dinv, c2b, x, 0);

    // A = user_out @ m1W_top -> g rows [0,100000) ; B = prod_out @ m1W_bot -> g rows [100000,150000)
    gemm_rows<256><<<NUM_USERS / 16, 256, 0, stream>>>(x, m1W, nullptr, nullptr, nullptr, g, 0);
    gemm_rows<256><<<NUM_PRODUCTS / 16, 256, 0, stream>>>(x + (size_t)NUM_USERS * D, m1W + 256 * 256,
                                                          nullptr, nullptr, nullptr, g, NUM_USERS);

    // preds[e] = relu(A[u]+B[p]+m1b) . m2w + m2b
    edge_mlp<<<NUM_EDGES / 4, 256, 0, stream>>>(g, ei, m1b, m2w, m2b, preds, NUM_EDGES);
}

// Round 2
// 1252.983 us; speedup vs baseline: 1.6699x; 1.6699x over previous
//
#include <hip/hip_runtime.h>
#include <hip/hip_bf16.h>
#include <cstdint>

#define NUM_USERS 100000
#define NUM_PRODUCTS 50000
#define N_NODES 150000
#define NUM_EDGES 250000
#define D 256

typedef __attribute__((ext_vector_type(8))) short bf16x8;
typedef __attribute__((ext_vector_type(4))) float f32x4;
typedef __attribute__((ext_vector_type(4))) unsigned short u16x4;

__device__ __forceinline__ unsigned short f2bf(float f) {
    union { float f; unsigned u; } x; x.f = f;
    unsigned r = x.u + 0x7fff + ((x.u >> 16) & 1);
    return (unsigned short)(r >> 16);
}
__device__ __forceinline__ float bf2f(unsigned short h) {
    union { unsigned u; float f; } x; x.u = ((unsigned)h) << 16;
    return x.f;
}

// ---------------------------------------------------------------------------
// Degree / CSR construction (unchanged from round 1)
// ---------------------------------------------------------------------------
__global__ __launch_bounds__(256) void count_deg(const int* __restrict__ ei, int* __restrict__ cnt, int E) {
    int e = blockIdx.x * 256 + threadIdx.x;
    if (e < E) {
        atomicAdd(&cnt[ei[e]], 1);
        atomicAdd(&cnt[ei[E + e]], 1);
    }
}

__global__ __launch_bounds__(256) void compute_dinv(const int* __restrict__ cnt, float* __restrict__ dinv, int N) {
    int n = blockIdx.x * 256 + threadIdx.x;
    if (n < N) dinv[n] = rsqrtf((float)(cnt[n] + 1));
}

#define SCAN_CHUNK 1024

__global__ __launch_bounds__(256) void scan_partials(const int* __restrict__ cnt, int* __restrict__ bsum, int N) {
    __shared__ int sdata[256];
    int base = blockIdx.x * SCAN_CHUNK;
    int t = threadIdx.x;
    int s = 0;
#pragma unroll
    for (int i = 0; i < 4; i++) {
        int idx = base + t * 4 + i;
        if (idx < N) s += cnt[idx];
    }
    sdata[t] = s;
    __syncthreads();
    for (int off = 128; off > 0; off >>= 1) {
        if (t < off) sdata[t] += sdata[t + off];
        __syncthreads();
    }
    if (t == 0) bsum[blockIdx.x] = sdata[0];
}

__global__ __launch_bounds__(256) void scan_bsums(const int* __restrict__ bsum, int* __restrict__ bscan,
                                                  int NB, int* __restrict__ offs, int N) {
    __shared__ int s[256];
    int t = threadIdx.x;
    int v = (t < NB) ? bsum[t] : 0;
    s[t] = v;
    __syncthreads();
    for (int off = 1; off < 256; off <<= 1) {
        int x = (t >= off) ? s[t - off] : 0;
        __syncthreads();
        s[t] += x;
        __syncthreads();
    }
    if (t < NB) bscan[t] = s[t] - v;
    if (t == 255) offs[N] = s[255];
}

__global__ __launch_bounds__(256) void scan_final(const int* __restrict__ cnt, const int* __restrict__ bscan,
                                                  int* __restrict__ offs, int N) {
    __shared__ int sdata[256];
    int base = blockIdx.x * SCAN_CHUNK;
    int t = threadIdx.x;
    int v[4];
    int loc = 0;
#pragma unroll
    for (int i = 0; i < 4; i++) {
        int idx = base + t * 4 + i;
        v[i] = (idx < N) ? cnt[idx] : 0;
        loc += v[i];
    }
    int mine = loc;
    sdata[t] = loc;
    __syncthreads();
    for (int off = 1; off < 256; off <<= 1) {
        int x = (t >= off) ? sdata[t - off] : 0;
        __syncthreads();
        sdata[t] += x;
        __syncthreads();
    }
    int pre = sdata[t] - mine + bscan[blockIdx.x];
#pragma unroll
    for (int i = 0; i < 4; i++) {
        int idx = base + t * 4 + i;
        if (idx < N) offs[idx] = pre;
        pre += v[i];
    }
}

__global__ __launch_bounds__(256) void fill_adj(const int* __restrict__ ei, const int* __restrict__ offs,
                                                int* __restrict__ cursor, int* __restrict__ adj, int E) {
    int e = blockIdx.x * 256 + threadIdx.x;
    if (e >= E) return;
    int u = ei[e];
    int p = ei[E + e];
    int pos = atomicAdd(&cursor[u], 1);
    adj[offs[u] + pos] = p;
    pos = atomicAdd(&cursor[p], 1);
    adj[offs[p] + pos] = u;
}

// ---------------------------------------------------------------------------
// Weight transpose + hi/lo split: W[K][256] f32 -> Wt_h/Wt_l [256][K] bf16
// ---------------------------------------------------------------------------
__global__ __launch_bounds__(256) void convW(const float* __restrict__ W, unsigned short* __restrict__ Wth,
                                             unsigned short* __restrict__ Wtl, int K) {
    int n = threadIdx.x;
    int k = blockIdx.x;
    float v = W[(size_t)k * 256 + n];
    unsigned short h = f2bf(v);
    Wth[(size_t)n * K + k] = h;
    Wtl[(size_t)n * K + k] = f2bf(v - bf2f(h));
}

// feature split (no transpose): f32 -> hi/lo bf16 planes
__global__ __launch_bounds__(256) void splitF(const float* __restrict__ in, unsigned short* __restrict__ h,
                                              unsigned short* __restrict__ l, int n4) {
    int i = blockIdx.x * 256 + threadIdx.x;
    if (i >= n4) return;
    f32x4 v = *(const f32x4*)(in + (size_t)i * 4);
    u16x4 hv, lv;
#pragma unroll
    for (int j = 0; j < 4; j++) {
        unsigned short hh = f2bf(v[j]);
        hv[j] = hh;
        lv[j] = f2bf(v[j] - bf2f(hh));
    }
    *(u16x4*)(h + (size_t)i * 4) = hv;
    *(u16x4*)(l + (size_t)i * 4) = lv;
}

// ---------------------------------------------------------------------------
// Split-bf16 MFMA GEMM.  C[128x128] tile per block, 4 waves (2x2), each wave
// 64x64 via 4x4 frags of 16x16x32 bf16 MFMA.  A,B staged via global_load_lds
// (16B) with inverse-swizzled global source + XOR-swizzled LDS reads (T2).
// acc = Ah*Bh + Ah*Bl + Al*Bh  (split-precision, ~16-bit mantissa).
// MODE 0: outF = v               (m1 GEMMs, f32 out)
// MODE 1: out planes = v + bias + addv   (input transforms)
// MODE 2: out planes = v * scale[row]    (conv pre-aggregation)
// ---------------------------------------------------------------------------
__device__ __forceinline__ void stage_tile(const unsigned short* __restrict__ plane, int row0, int rclamp,
                                           int ldK, int koff, char* ldsbase, int t) {
#pragma unroll
    for (int i = 0; i < 4; i++) {
        int chunk = i * 256 + t;        // 16B chunk; 8 chunks per 64-elem row
        int r = chunk >> 3;
        int c = chunk & 7;
        int grow = row0 + r;
        if (grow > rclamp) grow = rclamp;
        const unsigned short* src = plane + (size_t)grow * ldK + koff + ((c ^ (r & 7)) << 3);
        __builtin_amdgcn_global_load_lds((const __attribute__((address_space(1))) unsigned int*)src,
                                         (__attribute__((address_space(3))) unsigned int*)(ldsbase + chunk * 16),
                                         16, 0, 0);
    }
}

template <int K, int MODE>
__global__ __launch_bounds__(256, 2) void gemm_mfma(
    const unsigned short* __restrict__ Ah, const unsigned short* __restrict__ Al,  // [Mrows][K]
    const unsigned short* __restrict__ Bh, const unsigned short* __restrict__ Bl,  // [256][K] (transposed W)
    const float* __restrict__ bias, const float* __restrict__ addv,                // MODE1
    const float* __restrict__ scale,                                               // MODE2
    float* __restrict__ outF,                                                      // MODE0
    unsigned short* __restrict__ outH, unsigned short* __restrict__ outL,          // MODE1/2
    int Mrows, int out_base) {
    __shared__ char lds[65536];
    const int t = threadIdx.x;
    const int lane = t & 63;
    const int wid = t >> 6;
    const int wr = wid >> 1, wc = wid & 1;
    const int row0 = blockIdx.x * 128;
    const int col0 = blockIdx.y * 128;
    const int l15 = lane & 15;
    const int l4 = lane >> 4;

    char* ldsAh = lds;
    char* ldsAl = lds + 16384;
    char* ldsBh = lds + 32768;
    char* ldsBl = lds + 49152;

    f32x4 acc[4][4];
#pragma unroll
    for (int i = 0; i < 4; i++)
#pragma unroll
        for (int j = 0; j < 4; j++)
#pragma unroll
            for (int q = 0; q < 4; q++) acc[i][j][q] = 0.f;

    for (int ks = 0; ks < K / 64; ks++) {
        if (ks) __syncthreads();
        int koff = ks * 64;
        stage_tile(Ah, row0, Mrows - 1, K, koff, ldsAh, t);
        stage_tile(Al, row0, Mrows - 1, K, koff, ldsAl, t);
        stage_tile(Bh, col0, 255, K, koff, ldsBh, t);
        stage_tile(Bl, col0, 255, K, koff, ldsBl, t);
        asm volatile("s_waitcnt vmcnt(0)" ::: "memory");
        __syncthreads();
#pragma unroll
        for (int kk = 0; kk < 2; kk++) {
            int kc = kk * 4 + l4;       // 16B k-chunk index within row (0..7)
            bf16x8 ah[4], al[4], bh[4], bl[4];
#pragma unroll
            for (int mf = 0; mf < 4; mf++) {
                int r = wr * 64 + mf * 16 + l15;
                int pc = (kc ^ (r & 7)) << 4;
                ah[mf] = *(const bf16x8*)(ldsAh + r * 128 + pc);
                al[mf] = *(const bf16x8*)(ldsAl + r * 128 + pc);
            }
#pragma unroll
            for (int nf = 0; nf < 4; nf++) {
                int r = wc * 64 + nf * 16 + l15;
                int pc = (kc ^ (r & 7)) << 4;
                bh[nf] = *(const bf16x8*)(ldsBh + r * 128 + pc);
                bl[nf] = *(const bf16x8*)(ldsBl + r * 128 + pc);
            }
#pragma unroll
            for (int mf = 0; mf < 4; mf++)
#pragma unroll
                for (int nf = 0; nf < 4; nf++) {
                    acc[mf][nf] = __builtin_amdgcn_mfma_f32_16x16x32_bf16(ah[mf], bh[nf], acc[mf][nf], 0, 0, 0);
                    acc[mf][nf] = __builtin_amdgcn_mfma_f32_16x16x32_bf16(ah[mf], bl[nf], acc[mf][nf], 0, 0, 0);
                    acc[mf][nf] = __builtin_amdgcn_mfma_f32_16x16x32_bf16(al[mf], bh[nf], acc[mf][nf], 0, 0, 0);
                }
        }
    }

    // epilogue through LDS for coalesced stores
    __syncthreads();
    float* ldsC = (float*)lds;
#pragma unroll
    for (int mf = 0; mf < 4; mf++)
#pragma unroll
        for (int nf = 0; nf < 4; nf++) {
            int r = wr * 64 + mf * 16 + l4 * 4;
            int c = wc * 64 + nf * 16 + l15;
#pragma unroll
            for (int j = 0; j < 4; j++) ldsC[(r + j) * 128 + c] = acc[mf][nf][j];
        }
    __syncthreads();

    const int cg = t & 31;   // col group: cols cg*4..cg*4+3
    const int r0 = t >> 5;   // 8 rows per pass
#pragma unroll
    for (int i = 0; i < 16; i++) {
        int r = r0 + i * 8;
        int grow = row0 + r;
        if (grow >= Mrows) continue;
        f32x4 v = *(const f32x4*)&ldsC[r * 128 + cg * 4];
        int gc = col0 + cg * 4;
        if (MODE == 1) {
            f32x4 bv = *(const f32x4*)(bias + gc);
            f32x4 av = *(const f32x4*)(addv + (size_t)grow * 256 + gc);
            v += bv + av;
        } else if (MODE == 2) {
            v *= scale[grow];
        }
        size_t ob = (size_t)(out_base + grow) * 256 + gc;
        if (MODE == 0) {
            *(f32x4*)(outF + ob) = v;
        } else {
            u16x4 hv, lv;
#pragma unroll
            for (int j = 0; j < 4; j++) {
                unsigned short h = f2bf(v[j]);
                hv[j] = h;
                lv[j] = f2bf(v[j] - bf2f(h));
            }
            *(u16x4*)(outH + ob) = hv;
            *(u16x4*)(outL + ob) = lv;
        }
    }
}

// ---------------------------------------------------------------------------
// GCN aggregation on hi/lo planes
// ---------------------------------------------------------------------------
__global__ __launch_bounds__(256) void gcn_aggregate_bf(
    const unsigned short* __restrict__ gh, const unsigned short* __restrict__ gl,
    const int* __restrict__ offs, const int* __restrict__ adj,
    const float* __restrict__ dinv, const float* __restrict__ bias,
    unsigned short* __restrict__ xh, unsigned short* __restrict__ xl, int do_relu) {
    int d = blockIdx.x;
    int c = threadIdx.x;
    size_t rb = (size_t)d * D;
    float a = bf2f(gh[rb + c]) + bf2f(gl[rb + c]);
    int beg = offs[d], end = offs[d + 1];
    for (int i = beg; i < end; ++i) {
        size_t sb = (size_t)adj[i] * D;
        a += bf2f(gh[sb + c]) + bf2f(gl[sb + c]);
    }
    float v = fmaf(dinv[d], a, bias[c]);
    if (do_relu) v = fmaxf(v, 0.f);
    unsigned short h = f2bf(v);
    xh[rb + c] = h;
    xl[rb + c] = f2bf(v - bf2f(h));
}

// ---------------------------------------------------------------------------
// Edge MLP: preds[e] = relu(A[u] + B[p] + m1b) . m2w + m2b (one wave per edge)
// ---------------------------------------------------------------------------
__global__ __launch_bounds__(256) void edge_mlp(
    const float* __restrict__ ab, const int* __restrict__ ei,
    const float* __restrict__ m1b, const float* __restrict__ m2w, const float* __restrict__ m2b,
    float* __restrict__ preds, int E) {
    int wave = threadIdx.x >> 6;
    int lane = threadIdx.x & 63;
    int e = blockIdx.x * 4 + wave;
    if (e >= E) return;
    int u = ei[e];
    int p = ei[E + e];
    int c0 = lane * 4;
    f32x4 au = *(const f32x4*)&ab[(size_t)u * D + c0];
    f32x4 bp = *(const f32x4*)&ab[(size_t)p * D + c0];
    f32x4 bb = *(const f32x4*)&m1b[c0];
    f32x4 w = *(const f32x4*)&m2w[c0];
    float h0 = fmaxf(au[0] + bp[0] + bb[0], 0.f);
    float h1 = fmaxf(au[1] + bp[1] + bb[1], 0.f);
    float h2 = fmaxf(au[2] + bp[2] + bb[2], 0.f);
    float h3 = fmaxf(au[3] + bp[3] + bb[3], 0.f);
    float partial = h0 * w[0] + h1 * w[1] + h2 * w[2] + h3 * w[3];
#pragma unroll
    for (int off = 32; off > 0; off >>= 1) partial += __shfl_down(partial, off);
    if (lane == 0) preds[e] = partial + m2b[0];
}

// ---------------------------------------------------------------------------
extern "C" void kernel_launch(void* const* d_in, const int* in_sizes, int n_in,
                              void* d_out, int out_size, void* d_ws, size_t ws_size,
                              hipStream_t stream) {
    const int* ei = (const int*)d_in[0];
    const float* user_feat = (const float*)d_in[1];
    const float* prod_feat = (const float*)d_in[2];
    const float* user_emb = (const float*)d_in[3];
    const float* prod_emb = (const float*)d_in[4];
    const float* uW = (const float*)d_in[5];
    const float* ub = (const float*)d_in[6];
    const float* pW = (const float*)d_in[7];
    const float* pb = (const float*)d_in[8];
    const float* c1W = (const float*)d_in[9];
    const float* c1b = (const float*)d_in[10];
    const float* c2W = (const float*)d_in[11];
    const float* c2b = (const float*)d_in[12];
    const float* m1W = (const float*)d_in[13];
    const float* m1b = (const float*)d_in[14];
    const float* m2w = (const float*)d_in[15];
    const float* m2b = (const float*)d_in[16];
    float* preds = (float*)d_out;

    uint8_t* ws = (uint8_t*)d_ws;
    size_t off = 0;
    auto alloc = [&](size_t bytes) {
        size_t o = off;
        off = (off + bytes + 255) & ~(size_t)255;
        return o;
    };
    const size_t NROW = (size_t)N_NODES * D;   // 38.4M elems
    unsigned short* xh = (unsigned short*)(ws + alloc(NROW * 2));
    unsigned short* xl = (unsigned short*)(ws + alloc(NROW * 2));
    uint8_t* Greg = ws + alloc(NROW * 4);      // union: gh/gl planes | ab f32 | feature planes
    unsigned short* gh = (unsigned short*)Greg;
    unsigned short* gl = gh + NROW;
    float* ab = (float*)Greg;
    unsigned short* ufh = (unsigned short*)Greg;
    unsigned short* ufl = ufh + (size_t)NUM_USERS * 128;
    unsigned short* pfh = ufl + (size_t)NUM_USERS * 128;
    unsigned short* pfl = pfh + (size_t)NUM_PRODUCTS * 128;

    unsigned short* uWth = (unsigned short*)(ws + alloc(256 * 128 * 2));
    unsigned short* uWtl = (unsigned short*)(ws + alloc(256 * 128 * 2));
    unsigned short* pWth = (unsigned short*)(ws + alloc(256 * 128 * 2));
    unsigned short* pWtl = (unsigned short*)(ws + alloc(256 * 128 * 2));
    unsigned short* c1h = (unsigned short*)(ws + alloc(256 * 256 * 2));
    unsigned short* c1l = (unsigned short*)(ws + alloc(256 * 256 * 2));
    unsigned short* c2h = (unsigned short*)(ws + alloc(256 * 256 * 2));
    unsigned short* c2l = (unsigned short*)(ws + alloc(256 * 256 * 2));
    unsigned short* m1th = (unsigned short*)(ws + alloc(256 * 256 * 2));
    unsigned short* m1tl = (unsigned short*)(ws + alloc(256 * 256 * 2));
    unsigned short* m1bh = (unsigned short*)(ws + alloc(256 * 256 * 2));
    unsigned short* m1bl = (unsigned short*)(ws + alloc(256 * 256 * 2));

    float* dinv = (float*)(ws + alloc((size_t)N_NODES * 4));
    int* cnt = (int*)(ws + alloc((size_t)N_NODES * 4));
    int* cursor = (int*)(ws + alloc((size_t)N_NODES * 4));
    int* offs = (int*)(ws + alloc((size_t)(N_NODES + 1) * 4));
    int* adj = (int*)(ws + alloc((size_t)2 * NUM_EDGES * 4));
    int* bsum = (int*)(ws + alloc(4096));
    int* bscan = (int*)(ws + alloc(4096));

    const int NB = (N_NODES + SCAN_CHUNK - 1) / SCAN_CHUNK;

    hipMemsetAsync(cnt, 0, (size_t)N_NODES * 4, stream);
    hipMemsetAsync(cursor, 0, (size_t)N_NODES * 4, stream);

    // CSR + norm
    count_deg<<<(NUM_EDGES + 255) / 256, 256, 0, stream>>>(ei, cnt, NUM_EDGES);
    compute_dinv<<<(N_NODES + 255) / 256, 256, 0, stream>>>(cnt, dinv, N_NODES);
    scan_partials<<<NB, 256, 0, stream>>>(cnt, bsum, N_NODES);
    scan_bsums<<<1, 256, 0, stream>>>(bsum, bscan, NB, offs, N_NODES);
    scan_final<<<NB, 256, 0, stream>>>(cnt, bscan, offs, N_NODES);
    fill_adj<<<(NUM_EDGES + 255) / 256, 256, 0, stream>>>(ei, offs, cursor, adj, NUM_EDGES);

    // weight transpose+split
    convW<<<128, 256, 0, stream>>>(uW, uWth, uWtl, 128);
    convW<<<128, 256, 0, stream>>>(pW, pWth, pWtl, 128);
    convW<<<256, 256, 0, stream>>>(c1W, c1h, c1l, 256);
    convW<<<256, 256, 0, stream>>>(c2W, c2h, c2l, 256);
    convW<<<256, 256, 0, stream>>>(m1W, m1th, m1tl, 256);
    convW<<<256, 256, 0, stream>>>(m1W + 256 * 256, m1bh, m1bl, 256);

    // feature split (into G region; free until conv1 output)
    splitF<<<(NUM_USERS * 128 / 4 + 255) / 256, 256, 0, stream>>>(user_feat, ufh, ufl, NUM_USERS * 128 / 4);
    splitF<<<(NUM_PRODUCTS * 128 / 4 + 255) / 256, 256, 0, stream>>>(prod_feat, pfh, pfl, NUM_PRODUCTS * 128 / 4);

    const int TU = (NUM_USERS + 127) / 128;      // 782
    const int TP = (NUM_PRODUCTS + 127) / 128;   // 391
    const int TN = (N_NODES + 127) / 128;        // 1172

    // input transforms: x = feat @ W + b + emb
    gemm_mfma<128, 1><<<dim3(TU, 2), 256, 0, stream>>>(ufh, ufl, uWth, uWtl, ub, user_emb, nullptr,
                                                       nullptr, xh, xl, NUM_USERS, 0);
    gemm_mfma<128, 1><<<dim3(TP, 2), 256, 0, stream>>>(pfh, pfl, pWth, pWtl, pb, prod_emb, nullptr,
                                                       nullptr, xh, xl, NUM_PRODUCTS, NUM_USERS);

    // conv1: g = (x @ c1W) * dinv ; x = relu(dinv * (g[d] + sum g[s]) + c1b)
    gemm_mfma<256, 2><<<dim3(TN, 2), 256, 0, stream>>>(xh, xl, c1h, c1l, nullptr, nullptr, dinv,
                                                       nullptr, gh, gl, N_NODES, 0);
    gcn_aggregate_bf<<<N_NODES, 256, 0, stream>>>(gh, gl, offs, adj, dinv, c1b, xh, xl, 1);

    // conv2
    gemm_mfma<256, 2><<<dim3(TN, 2), 256, 0, stream>>>(xh, xl, c2h, c2l, nullptr, nullptr, dinv,
                                                       nullptr, gh, gl, N_NODES, 0);
    gcn_aggregate_bf<<<N_NODES, 256, 0, stream>>>(gh, gl, offs, adj, dinv, c2b, xh, xl, 0);

    // m1: A = user_out @ m1W_top ; B = prod_out @ m1W_bot  -> ab (f32, aliases G region)
    gemm_mfma<256, 0><<<dim3(TU, 2), 256, 0, stream>>>(xh, xl, m1th, m1tl, nullptr, nullptr, nullptr,
                                                       ab, nullptr, nullptr, NUM_USERS, 0);
    gemm_mfma<256, 0><<<dim3(TP, 2), 256, 0, stream>>>(xh + (size_t)NUM_USERS * D, xl + (size_t)NUM_USERS * D,
                                                       m1bh, m1bl, nullptr, nullptr, nullptr,
                                                       ab, nullptr, nullptr, NUM_PRODUCTS, NUM_USERS);

    // preds
    edge_mlp<<<NUM_EDGES / 4, 256, 0, stream>>>(ab, ei, m1b, m2w, m2b, preds, NUM_EDGES);
}

// Round 3
// 1027.562 us; speedup vs baseline: 2.0363x; 1.2194x over previous
//
#include <hip/hip_runtime.h>
#include <hip/hip_bf16.h>
#include <cstdint>

#define NUM_USERS 100000
#define NUM_PRODUCTS 50000
#define N_NODES 150000
#define NUM_EDGES 250000
#define D 256

typedef __attribute__((ext_vector_type(8))) short bf16x8;
typedef __attribute__((ext_vector_type(4))) float f32x4;
typedef __attribute__((ext_vector_type(4))) unsigned short u16x4;

__device__ __forceinline__ unsigned short f2bf(float f) {
    union { float f; unsigned u; } x; x.f = f;
    unsigned r = x.u + 0x7fff + ((x.u >> 16) & 1);
    return (unsigned short)(r >> 16);
}
__device__ __forceinline__ float bf2f(unsigned short h) {
    union { unsigned u; float f; } x; x.u = ((unsigned)h) << 16;
    return x.f;
}

// ---------------------------------------------------------------------------
// Degree / CSR construction
// ---------------------------------------------------------------------------
__global__ __launch_bounds__(256) void count_deg(const int* __restrict__ ei, int* __restrict__ cnt, int E) {
    int e = blockIdx.x * 256 + threadIdx.x;
    if (e < E) {
        atomicAdd(&cnt[ei[e]], 1);
        atomicAdd(&cnt[ei[E + e]], 1);
    }
}

__global__ __launch_bounds__(256) void compute_dinv(const int* __restrict__ cnt, float* __restrict__ dinv, int N) {
    int n = blockIdx.x * 256 + threadIdx.x;
    if (n < N) dinv[n] = rsqrtf((float)(cnt[n] + 1));
}

#define SCAN_CHUNK 1024

__global__ __launch_bounds__(256) void scan_partials(const int* __restrict__ cnt, int* __restrict__ bsum, int N) {
    __shared__ int sdata[256];
    int base = blockIdx.x * SCAN_CHUNK;
    int t = threadIdx.x;
    int s = 0;
#pragma unroll
    for (int i = 0; i < 4; i++) {
        int idx = base + t * 4 + i;
        if (idx < N) s += cnt[idx];
    }
    sdata[t] = s;
    __syncthreads();
    for (int off = 128; off > 0; off >>= 1) {
        if (t < off) sdata[t] += sdata[t + off];
        __syncthreads();
    }
    if (t == 0) bsum[blockIdx.x] = sdata[0];
}

__global__ __launch_bounds__(256) void scan_bsums(const int* __restrict__ bsum, int* __restrict__ bscan,
                                                  int NB, int* __restrict__ offs, int N) {
    __shared__ int s[256];
    int t = threadIdx.x;
    int v = (t < NB) ? bsum[t] : 0;
    s[t] = v;
    __syncthreads();
    for (int off = 1; off < 256; off <<= 1) {
        int x = (t >= off) ? s[t - off] : 0;
        __syncthreads();
        s[t] += x;
        __syncthreads();
    }
    if (t < NB) bscan[t] = s[t] - v;
    if (t == 255) offs[N] = s[255];
}

__global__ __launch_bounds__(256) void scan_final(const int* __restrict__ cnt, const int* __restrict__ bscan,
                                                  int* __restrict__ offs, int N) {
    __shared__ int sdata[256];
    int base = blockIdx.x * SCAN_CHUNK;
    int t = threadIdx.x;
    int v[4];
    int loc = 0;
#pragma unroll
    for (int i = 0; i < 4; i++) {
        int idx = base + t * 4 + i;
        v[i] = (idx < N) ? cnt[idx] : 0;
        loc += v[i];
    }
    int mine = loc;
    sdata[t] = loc;
    __syncthreads();
    for (int off = 1; off < 256; off <<= 1) {
        int x = (t >= off) ? sdata[t - off] : 0;
        __syncthreads();
        sdata[t] += x;
        __syncthreads();
    }
    int pre = sdata[t] - mine + bscan[blockIdx.x];
#pragma unroll
    for (int i = 0; i < 4; i++) {
        int idx = base + t * 4 + i;
        if (idx < N) offs[idx] = pre;
        pre += v[i];
    }
}

__global__ __launch_bounds__(256) void fill_adj(const int* __restrict__ ei, const int* __restrict__ offs,
                                                int* __restrict__ cursor, int* __restrict__ adj, int E) {
    int e = blockIdx.x * 256 + threadIdx.x;
    if (e >= E) return;
    int u = ei[e];
    int p = ei[E + e];
    int pos = atomicAdd(&cursor[u], 1);
    adj[offs[u] + pos] = p;
    pos = atomicAdd(&cursor[p], 1);
    adj[offs[p] + pos] = u;
}

// ---------------------------------------------------------------------------
// Weight transpose + hi/lo split: W[K][256] f32 -> Wt_h/Wt_l [256][K] bf16
// ---------------------------------------------------------------------------
__global__ __launch_bounds__(256) void convW(const float* __restrict__ W, unsigned short* __restrict__ Wth,
                                             unsigned short* __restrict__ Wtl, int K) {
    int n = threadIdx.x;
    int k = blockIdx.x;
    float v = W[(size_t)k * 256 + n];
    unsigned short h = f2bf(v);
    Wth[(size_t)n * K + k] = h;
    Wtl[(size_t)n * K + k] = f2bf(v - bf2f(h));
}

// feature split (no transpose): f32 -> hi/lo bf16 planes
__global__ __launch_bounds__(256) void splitF(const float* __restrict__ in, unsigned short* __restrict__ h,
                                              unsigned short* __restrict__ l, int n4) {
    int i = blockIdx.x * 256 + threadIdx.x;
    if (i >= n4) return;
    f32x4 v = *(const f32x4*)(in + (size_t)i * 4);
    u16x4 hv, lv;
#pragma unroll
    for (int j = 0; j < 4; j++) {
        unsigned short hh = f2bf(v[j]);
        hv[j] = hh;
        lv[j] = f2bf(v[j] - bf2f(hh));
    }
    *(u16x4*)(h + (size_t)i * 4) = hv;
    *(u16x4*)(l + (size_t)i * 4) = lv;
}

// ---------------------------------------------------------------------------
// Split-bf16 MFMA GEMM.  C[128x128] tile per block, 4 waves (2x2), each wave
// 64x64 via 4x4 frags of 16x16x32 bf16 MFMA.  A,B staged via global_load_lds
// (16B) with inverse-swizzled global source + XOR-swizzled LDS reads (T2).
// acc = Ah*Bh + Ah*Bl + Al*Bh  (split-precision, ~16-bit mantissa).
// MODE 0: outF = v                        (m1 GEMMs, f32 out)
// MODE 1: out planes = v + bias + addv    (input transforms)
// MODE 2: outF = v * scale[row]           (conv pre-aggregation, f32 out)
// ---------------------------------------------------------------------------
__device__ __forceinline__ void stage_tile(const unsigned short* __restrict__ plane, int row0, int rclamp,
                                           int ldK, int koff, char* ldsbase, int t) {
#pragma unroll
    for (int i = 0; i < 4; i++) {
        int chunk = i * 256 + t;        // 16B chunk; 8 chunks per 64-elem row
        int r = chunk >> 3;
        int c = chunk & 7;
        int grow = row0 + r;
        if (grow > rclamp) grow = rclamp;
        const unsigned short* src = plane + (size_t)grow * ldK + koff + ((c ^ (r & 7)) << 3);
        __builtin_amdgcn_global_load_lds((const __attribute__((address_space(1))) unsigned int*)src,
                                         (__attribute__((address_space(3))) unsigned int*)(ldsbase + chunk * 16),
                                         16, 0, 0);
    }
}

template <int K, int MODE>
__global__ __launch_bounds__(256, 2) void gemm_mfma(
    const unsigned short* __restrict__ Ah, const unsigned short* __restrict__ Al,  // [Mrows][K]
    const unsigned short* __restrict__ Bh, const unsigned short* __restrict__ Bl,  // [256][K] (transposed W)
    const float* __restrict__ bias, const float* __restrict__ addv,                // MODE1
    const float* __restrict__ scale,                                               // MODE2
    float* __restrict__ outF,                                                      // MODE0/2
    unsigned short* __restrict__ outH, unsigned short* __restrict__ outL,          // MODE1
    int Mrows, int out_base) {
    __shared__ char lds[65536];
    const int t = threadIdx.x;
    const int lane = t & 63;
    const int wid = t >> 6;
    const int wr = wid >> 1, wc = wid & 1;
    const int row0 = blockIdx.x * 128;
    const int col0 = blockIdx.y * 128;
    const int l15 = lane & 15;
    const int l4 = lane >> 4;

    char* ldsAh = lds;
    char* ldsAl = lds + 16384;
    char* ldsBh = lds + 32768;
    char* ldsBl = lds + 49152;

    f32x4 acc[4][4];
#pragma unroll
    for (int i = 0; i < 4; i++)
#pragma unroll
        for (int j = 0; j < 4; j++)
#pragma unroll
            for (int q = 0; q < 4; q++) acc[i][j][q] = 0.f;

    for (int ks = 0; ks < K / 64; ks++) {
        if (ks) __syncthreads();
        int koff = ks * 64;
        stage_tile(Ah, row0, Mrows - 1, K, koff, ldsAh, t);
        stage_tile(Al, row0, Mrows - 1, K, koff, ldsAl, t);
        stage_tile(Bh, col0, 255, K, koff, ldsBh, t);
        stage_tile(Bl, col0, 255, K, koff, ldsBl, t);
        asm volatile("s_waitcnt vmcnt(0)" ::: "memory");
        __syncthreads();
#pragma unroll
        for (int kk = 0; kk < 2; kk++) {
            int kc = kk * 4 + l4;       // 16B k-chunk index within row (0..7)
            bf16x8 ah[4], al[4], bh[4], bl[4];
#pragma unroll
            for (int mf = 0; mf < 4; mf++) {
                int r = wr * 64 + mf * 16 + l15;
                int pc = (kc ^ (r & 7)) << 4;
                ah[mf] = *(const bf16x8*)(ldsAh + r * 128 + pc);
                al[mf] = *(const bf16x8*)(ldsAl + r * 128 + pc);
            }
#pragma unroll
            for (int nf = 0; nf < 4; nf++) {
                int r = wc * 64 + nf * 16 + l15;
                int pc = (kc ^ (r & 7)) << 4;
                bh[nf] = *(const bf16x8*)(ldsBh + r * 128 + pc);
                bl[nf] = *(const bf16x8*)(ldsBl + r * 128 + pc);
            }
#pragma unroll
            for (int mf = 0; mf < 4; mf++)
#pragma unroll
                for (int nf = 0; nf < 4; nf++) {
                    acc[mf][nf] = __builtin_amdgcn_mfma_f32_16x16x32_bf16(ah[mf], bh[nf], acc[mf][nf], 0, 0, 0);
                    acc[mf][nf] = __builtin_amdgcn_mfma_f32_16x16x32_bf16(ah[mf], bl[nf], acc[mf][nf], 0, 0, 0);
                    acc[mf][nf] = __builtin_amdgcn_mfma_f32_16x16x32_bf16(al[mf], bh[nf], acc[mf][nf], 0, 0, 0);
                }
        }
    }

    // epilogue through LDS for coalesced stores
    __syncthreads();
    float* ldsC = (float*)lds;
#pragma unroll
    for (int mf = 0; mf < 4; mf++)
#pragma unroll
        for (int nf = 0; nf < 4; nf++) {
            int r = wr * 64 + mf * 16 + l4 * 4;
            int c = wc * 64 + nf * 16 + l15;
#pragma unroll
            for (int j = 0; j < 4; j++) ldsC[(r + j) * 128 + c] = acc[mf][nf][j];
        }
    __syncthreads();

    const int cg = t & 31;   // col group: cols cg*4..cg*4+3
    const int r0 = t >> 5;   // 8 rows per pass
#pragma unroll
    for (int i = 0; i < 16; i++) {
        int r = r0 + i * 8;
        int grow = row0 + r;
        if (grow >= Mrows) continue;
        f32x4 v = *(const f32x4*)&ldsC[r * 128 + cg * 4];
        int gc = col0 + cg * 4;
        if (MODE == 1) {
            f32x4 bv = *(const f32x4*)(bias + gc);
            f32x4 av = *(const f32x4*)(addv + (size_t)grow * 256 + gc);
            v += bv + av;
        } else if (MODE == 2) {
            v *= scale[grow];
        }
        size_t ob = (size_t)(out_base + grow) * 256 + gc;
        if (MODE == 1) {
            u16x4 hv, lv;
#pragma unroll
            for (int j = 0; j < 4; j++) {
                unsigned short h = f2bf(v[j]);
                hv[j] = h;
                lv[j] = f2bf(v[j] - bf2f(h));
            }
            *(u16x4*)(outH + ob) = hv;
            *(u16x4*)(outL + ob) = lv;
        } else {
            *(f32x4*)(outF + ob) = v;
        }
    }
}

// ---------------------------------------------------------------------------
// GCN aggregation, f32 gather: one wave per node, lane = 4 cols (16B loads),
// neighbor loop unrolled x2. out planes = split(relu?(dinv*(self+sum)+bias))
// ---------------------------------------------------------------------------
__global__ __launch_bounds__(256) void gcn_aggregate_f32(
    const float* __restrict__ g, const int* __restrict__ offs, const int* __restrict__ adj,
    const float* __restrict__ dinv, const float* __restrict__ bias,
    unsigned short* __restrict__ xh, unsigned short* __restrict__ xl, int do_relu) {
    int wave = threadIdx.x >> 6;
    int lane = threadIdx.x & 63;
    int d = blockIdx.x * 4 + wave;
    int c0 = lane * 4;

    f32x4 acc0 = *(const f32x4*)&g[(size_t)d * D + c0];   // self term
    f32x4 acc1 = {0.f, 0.f, 0.f, 0.f};
    int beg = offs[d], end = offs[d + 1];
    int i = beg;
    for (; i + 1 < end; i += 2) {
        int s0 = adj[i];
        int s1 = adj[i + 1];
        f32x4 v0 = *(const f32x4*)&g[(size_t)s0 * D + c0];
        f32x4 v1 = *(const f32x4*)&g[(size_t)s1 * D + c0];
        acc0 += v0;
        acc1 += v1;
    }
    if (i < end) {
        int s = adj[i];
        acc0 += *(const f32x4*)&g[(size_t)s * D + c0];
    }
    f32x4 acc = acc0 + acc1;

    float dv = dinv[d];
    f32x4 bv = *(const f32x4*)&bias[c0];
    u16x4 hv, lv;
#pragma unroll
    for (int j = 0; j < 4; j++) {
        float v = fmaf(dv, acc[j], bv[j]);
        if (do_relu) v = fmaxf(v, 0.f);
        unsigned short h = f2bf(v);
        hv[j] = h;
        lv[j] = f2bf(v - bf2f(h));
    }
    size_t ob = (size_t)d * D + c0;
    *(u16x4*)(xh + ob) = hv;
    *(u16x4*)(xl + ob) = lv;
}

// ---------------------------------------------------------------------------
// Edge MLP: preds[e] = relu(A[u] + B[p] + m1b) . m2w + m2b (one wave per edge)
// ---------------------------------------------------------------------------
__global__ __launch_bounds__(256) void edge_mlp(
    const float* __restrict__ ab, const int* __restrict__ ei,
    const float* __restrict__ m1b, const float* __restrict__ m2w, const float* __restrict__ m2b,
    float* __restrict__ preds, int E) {
    int wave = threadIdx.x >> 6;
    int lane = threadIdx.x & 63;
    int e = blockIdx.x * 4 + wave;
    if (e >= E) return;
    int u = ei[e];
    int p = ei[E + e];
    int c0 = lane * 4;
    f32x4 au = *(const f32x4*)&ab[(size_t)u * D + c0];
    f32x4 bp = *(const f32x4*)&ab[(size_t)p * D + c0];
    f32x4 bb = *(const f32x4*)&m1b[c0];
    f32x4 w = *(const f32x4*)&m2w[c0];
    float h0 = fmaxf(au[0] + bp[0] + bb[0], 0.f);
    float h1 = fmaxf(au[1] + bp[1] + bb[1], 0.f);
    float h2 = fmaxf(au[2] + bp[2] + bb[2], 0.f);
    float h3 = fmaxf(au[3] + bp[3] + bb[3], 0.f);
    float partial = h0 * w[0] + h1 * w[1] + h2 * w[2] + h3 * w[3];
#pragma unroll
    for (int off = 32; off > 0; off >>= 1) partial += __shfl_down(partial, off);
    if (lane == 0) preds[e] = partial + m2b[0];
}

// ---------------------------------------------------------------------------
extern "C" void kernel_launch(void* const* d_in, const int* in_sizes, int n_in,
                              void* d_out, int out_size, void* d_ws, size_t ws_size,
                              hipStream_t stream) {
    const int* ei = (const int*)d_in[0];
    const float* user_feat = (const float*)d_in[1];
    const float* prod_feat = (const float*)d_in[2];
    const float* user_emb = (const float*)d_in[3];
    const float* prod_emb = (const float*)d_in[4];
    const float* uW = (const float*)d_in[5];
    const float* ub = (const float*)d_in[6];
    const float* pW = (const float*)d_in[7];
    const float* pb = (const float*)d_in[8];
    const float* c1W = (const float*)d_in[9];
    const float* c1b = (const float*)d_in[10];
    const float* c2W = (const float*)d_in[11];
    const float* c2b = (const float*)d_in[12];
    const float* m1W = (const float*)d_in[13];
    const float* m1b = (const float*)d_in[14];
    const float* m2w = (const float*)d_in[15];
    const float* m2b = (const float*)d_in[16];
    float* preds = (float*)d_out;

    uint8_t* ws = (uint8_t*)d_ws;
    size_t off = 0;
    auto alloc = [&](size_t bytes) {
        size_t o = off;
        off = (off + bytes + 255) & ~(size_t)255;
        return o;
    };
    const size_t NROW = (size_t)N_NODES * D;   // 38.4M elems
    unsigned short* xh = (unsigned short*)(ws + alloc(NROW * 2));
    unsigned short* xl = (unsigned short*)(ws + alloc(NROW * 2));
    uint8_t* Greg = ws + alloc(NROW * 4);      // union: g f32 | ab f32 | feature planes
    float* gF = (float*)Greg;
    float* ab = (float*)Greg;
    unsigned short* ufh = (unsigned short*)Greg;
    unsigned short* ufl = ufh + (size_t)NUM_USERS * 128;
    unsigned short* pfh = ufl + (size_t)NUM_USERS * 128;
    unsigned short* pfl = pfh + (size_t)NUM_PRODUCTS * 128;

    unsigned short* uWth = (unsigned short*)(ws + alloc(256 * 128 * 2));
    unsigned short* uWtl = (unsigned short*)(ws + alloc(256 * 128 * 2));
    unsigned short* pWth = (unsigned short*)(ws + alloc(256 * 128 * 2));
    unsigned short* pWtl = (unsigned short*)(ws + alloc(256 * 128 * 2));
    unsigned short* c1h = (unsigned short*)(ws + alloc(256 * 256 * 2));
    unsigned short* c1l = (unsigned short*)(ws + alloc(256 * 256 * 2));
    unsigned short* c2h = (unsigned short*)(ws + alloc(256 * 256 * 2));
    unsigned short* c2l = (unsigned short*)(ws + alloc(256 * 256 * 2));
    unsigned short* m1th = (unsigned short*)(ws + alloc(256 * 256 * 2));
    unsigned short* m1tl = (unsigned short*)(ws + alloc(256 * 256 * 2));
    unsigned short* m1bh = (unsigned short*)(ws + alloc(256 * 256 * 2));
    unsigned short* m1bl = (unsigned short*)(ws + alloc(256 * 256 * 2));

    float* dinv = (float*)(ws + alloc((size_t)N_NODES * 4));
    int* cnt = (int*)(ws + alloc((size_t)N_NODES * 4));
    int* cursor = (int*)(ws + alloc((size_t)N_NODES * 4));
    int* offs = (int*)(ws + alloc((size_t)(N_NODES + 1) * 4));
    int* adj = (int*)(ws + alloc((size_t)2 * NUM_EDGES * 4));
    int* bsum = (int*)(ws + alloc(4096));
    int* bscan = (int*)(ws + alloc(4096));

    const int NB = (N_NODES + SCAN_CHUNK - 1) / SCAN_CHUNK;

    hipMemsetAsync(cnt, 0, (size_t)N_NODES * 4, stream);
    hipMemsetAsync(cursor, 0, (size_t)N_NODES * 4, stream);

    // CSR + norm
    count_deg<<<(NUM_EDGES + 255) / 256, 256, 0, stream>>>(ei, cnt, NUM_EDGES);
    compute_dinv<<<(N_NODES + 255) / 256, 256, 0, stream>>>(cnt, dinv, N_NODES);
    scan_partials<<<NB, 256, 0, stream>>>(cnt, bsum, N_NODES);
    scan_bsums<<<1, 256, 0, stream>>>(bsum, bscan, NB, offs, N_NODES);
    scan_final<<<NB, 256, 0, stream>>>(cnt, bscan, offs, N_NODES);
    fill_adj<<<(NUM_EDGES + 255) / 256, 256, 0, stream>>>(ei, offs, cursor, adj, NUM_EDGES);

    // weight transpose+split
    convW<<<128, 256, 0, stream>>>(uW, uWth, uWtl, 128);
    convW<<<128, 256, 0, stream>>>(pW, pWth, pWtl, 128);
    convW<<<256, 256, 0, stream>>>(c1W, c1h, c1l, 256);
    convW<<<256, 256, 0, stream>>>(c2W, c2h, c2l, 256);
    convW<<<256, 256, 0, stream>>>(m1W, m1th, m1tl, 256);
    convW<<<256, 256, 0, stream>>>(m1W + 256 * 256, m1bh, m1bl, 256);

    // feature split (into G region; free until conv1 output)
    splitF<<<(NUM_USERS * 128 / 4 + 255) / 256, 256, 0, stream>>>(user_feat, ufh, ufl, NUM_USERS * 128 / 4);
    splitF<<<(NUM_PRODUCTS * 128 / 4 + 255) / 256, 256, 0, stream>>>(prod_feat, pfh, pfl, NUM_PRODUCTS * 128 / 4);

    const int TU = (NUM_USERS + 127) / 128;      // 782
    const int TP = (NUM_PRODUCTS + 127) / 128;   // 391
    const int TN = (N_NODES + 127) / 128;        // 1172

    // input transforms: x = feat @ W + b + emb  (planes)
    gemm_mfma<128, 1><<<dim3(TU, 2), 256, 0, stream>>>(ufh, ufl, uWth, uWtl, ub, user_emb, nullptr,
                                                       nullptr, xh, xl, NUM_USERS, 0);
    gemm_mfma<128, 1><<<dim3(TP, 2), 256, 0, stream>>>(pfh, pfl, pWth, pWtl, pb, prod_emb, nullptr,
                                                       nullptr, xh, xl, NUM_PRODUCTS, NUM_USERS);

    // conv1: g = (x @ c1W) * dinv (f32) ; x = split(relu(dinv*(g[d]+sum g[s]) + c1b))
    gemm_mfma<256, 2><<<dim3(TN, 2), 256, 0, stream>>>(xh, xl, c1h, c1l, nullptr, nullptr, dinv,
                                                       gF, nullptr, nullptr, N_NODES, 0);
    gcn_aggregate_f32<<<N_NODES / 4, 256, 0, stream>>>(gF, offs, adj, dinv, c1b, xh, xl, 1);

    // conv2
    gemm_mfma<256, 2><<<dim3(TN, 2), 256, 0, stream>>>(xh, xl, c2h, c2l, nullptr, nullptr, dinv,
                                                       gF, nullptr, nullptr, N_NODES, 0);
    gcn_aggregate_f32<<<N_NODES / 4, 256, 0, stream>>>(gF, offs, adj, dinv, c2b, xh, xl, 0);

    // m1: A = user_out @ m1W_top ; B = prod_out @ m1W_bot  -> ab (f32, aliases G region)
    gemm_mfma<256, 0><<<dim3(TU, 2), 256, 0, stream>>>(xh, xl, m1th, m1tl, nullptr, nullptr, nullptr,
                                                       ab, nullptr, nullptr, NUM_USERS, 0);
    gemm_mfma<256, 0><<<dim3(TP, 2), 256, 0, stream>>>(xh + (size_t)NUM_USERS * D, xl + (size_t)NUM_USERS * D,
                                                       m1bh, m1bl, nullptr, nullptr, nullptr,
                                                       ab, nullptr, nullptr, NUM_PRODUCTS, NUM_USERS);

    // preds
    edge_mlp<<<NUM_EDGES / 4, 256, 0, stream>>>(ab, ei, m1b, m2w, m2b, preds, NUM_EDGES);
}

// Round 4
// 1021.605 us; speedup vs baseline: 2.0481x; 1.0058x over previous
//
#include <hip/hip_runtime.h>
#include <hip/hip_bf16.h>
#include <cstdint>

#define NUM_USERS 100000
#define NUM_PRODUCTS 50000
#define N_NODES 150000
#define NUM_EDGES 250000
#define D 256

typedef __attribute__((ext_vector_type(8))) short bf16x8;
typedef __attribute__((ext_vector_type(4))) float f32x4;
typedef __attribute__((ext_vector_type(4))) unsigned short u16x4;

__device__ __forceinline__ unsigned short f2bf(float f) {
    union { float f; unsigned u; } x; x.f = f;
    unsigned r = x.u + 0x7fff + ((x.u >> 16) & 1);
    return (unsigned short)(r >> 16);
}
__device__ __forceinline__ float bf2f(unsigned short h) {
    union { unsigned u; float f; } x; x.u = ((unsigned)h) << 16;
    return x.f;
}

// ---------------------------------------------------------------------------
// Degree / CSR construction
// ---------------------------------------------------------------------------
__global__ __launch_bounds__(256) void count_deg(const int* __restrict__ ei, int* __restrict__ cnt, int E) {
    int e = blockIdx.x * 256 + threadIdx.x;
    if (e < E) {
        atomicAdd(&cnt[ei[e]], 1);
        atomicAdd(&cnt[ei[E + e]], 1);
    }
}

__global__ __launch_bounds__(256) void compute_dinv(const int* __restrict__ cnt, float* __restrict__ dinv, int N) {
    int n = blockIdx.x * 256 + threadIdx.x;
    if (n < N) dinv[n] = rsqrtf((float)(cnt[n] + 1));
}

#define SCAN_CHUNK 1024

__global__ __launch_bounds__(256) void scan_partials(const int* __restrict__ cnt, int* __restrict__ bsum, int N) {
    __shared__ int sdata[256];
    int base = blockIdx.x * SCAN_CHUNK;
    int t = threadIdx.x;
    int s = 0;
#pragma unroll
    for (int i = 0; i < 4; i++) {
        int idx = base + t * 4 + i;
        if (idx < N) s += cnt[idx];
    }
    sdata[t] = s;
    __syncthreads();
    for (int off = 128; off > 0; off >>= 1) {
        if (t < off) sdata[t] += sdata[t + off];
        __syncthreads();
    }
    if (t == 0) bsum[blockIdx.x] = sdata[0];
}

__global__ __launch_bounds__(256) void scan_bsums(const int* __restrict__ bsum, int* __restrict__ bscan,
                                                  int NB, int* __restrict__ offs, int N) {
    __shared__ int s[256];
    int t = threadIdx.x;
    int v = (t < NB) ? bsum[t] : 0;
    s[t] = v;
    __syncthreads();
    for (int off = 1; off < 256; off <<= 1) {
        int x = (t >= off) ? s[t - off] : 0;
        __syncthreads();
        s[t] += x;
        __syncthreads();
    }
    if (t < NB) bscan[t] = s[t] - v;
    if (t == 255) offs[N] = s[255];
}

__global__ __launch_bounds__(256) void scan_final(const int* __restrict__ cnt, const int* __restrict__ bscan,
                                                  int* __restrict__ offs, int N) {
    __shared__ int sdata[256];
    int base = blockIdx.x * SCAN_CHUNK;
    int t = threadIdx.x;
    int v[4];
    int loc = 0;
#pragma unroll
    for (int i = 0; i < 4; i++) {
        int idx = base + t * 4 + i;
        v[i] = (idx < N) ? cnt[idx] : 0;
        loc += v[i];
    }
    int mine = loc;
    sdata[t] = loc;
    __syncthreads();
    for (int off = 1; off < 256; off <<= 1) {
        int x = (t >= off) ? sdata[t - off] : 0;
        __syncthreads();
        sdata[t] += x;
        __syncthreads();
    }
    int pre = sdata[t] - mine + bscan[blockIdx.x];
#pragma unroll
    for (int i = 0; i < 4; i++) {
        int idx = base + t * 4 + i;
        if (idx < N) offs[idx] = pre;
        pre += v[i];
    }
}

__global__ __launch_bounds__(256) void fill_adj(const int* __restrict__ ei, const int* __restrict__ offs,
                                                int* __restrict__ cursor, int* __restrict__ adj, int E) {
    int e = blockIdx.x * 256 + threadIdx.x;
    if (e >= E) return;
    int u = ei[e];
    int p = ei[E + e];
    int pos = atomicAdd(&cursor[u], 1);
    adj[offs[u] + pos] = p;
    pos = atomicAdd(&cursor[p], 1);
    adj[offs[p] + pos] = u;
}

// ---------------------------------------------------------------------------
// Weight transpose + hi/lo split: W[K][256] f32 -> Wt_h/Wt_l [256][K] bf16
// ---------------------------------------------------------------------------
__global__ __launch_bounds__(256) void convW(const float* __restrict__ W, unsigned short* __restrict__ Wth,
                                             unsigned short* __restrict__ Wtl, int K) {
    int n = threadIdx.x;
    int k = blockIdx.x;
    float v = W[(size_t)k * 256 + n];
    unsigned short h = f2bf(v);
    Wth[(size_t)n * K + k] = h;
    Wtl[(size_t)n * K + k] = f2bf(v - bf2f(h));
}

// feature split (no transpose): f32 -> hi/lo bf16 planes
__global__ __launch_bounds__(256) void splitF(const float* __restrict__ in, unsigned short* __restrict__ h,
                                              unsigned short* __restrict__ l, int n4) {
    int i = blockIdx.x * 256 + threadIdx.x;
    if (i >= n4) return;
    f32x4 v = *(const f32x4*)(in + (size_t)i * 4);
    u16x4 hv, lv;
#pragma unroll
    for (int j = 0; j < 4; j++) {
        unsigned short hh = f2bf(v[j]);
        hv[j] = hh;
        lv[j] = f2bf(v[j] - bf2f(hh));
    }
    *(u16x4*)(h + (size_t)i * 4) = hv;
    *(u16x4*)(l + (size_t)i * 4) = lv;
}

// ---------------------------------------------------------------------------
// Split-bf16 MFMA GEMM, BK=32.  C[128x128] per block, 4 waves (2x2), each
// wave 64x64 via 4x4 frags of 16x16x32 bf16 MFMA.
// hi+lo planes packed in ONE tile: 128 rows x 8 slots x 16B (128B rows);
// conceptual slot u = plane*4 + kc, stored at s = u ^ (r&7)  -> all 32 banks
// covered per 8 rows (2-way free).  Staged via global_load_lds(16B), linear
// LDS dest + pre-swizzled global source (T2 both-sides rule).
// LDS: A tile 16KB + B tile 16KB = 32KB -> 3 blocks/CU.
// acc = Ah*Bh + Ah*Bl + Al*Bh.
// MODE 0: outF = v ; MODE 1: planes = v+bias+addv ; MODE 2: outF = v*scale
// ---------------------------------------------------------------------------
__device__ __forceinline__ void stage_tile32(const unsigned short* __restrict__ ph,
                                             const unsigned short* __restrict__ pl,
                                             int row0, int rclamp, int ldK, int koff,
                                             char* ldsbase, int t) {
#pragma unroll
    for (int j = 0; j < 4; j++) {
        int chunk = j * 256 + t;        // 1024 chunks of 16B = 16KB tile
        int r = chunk >> 3;
        int s = chunk & 7;
        int u = s ^ (r & 7);            // conceptual slot: plane*4 + kc
        int kc = u & 3;
        int grow = row0 + r;
        if (grow > rclamp) grow = rclamp;
        const unsigned short* base = (u & 4) ? pl : ph;
        const unsigned short* src = base + (size_t)grow * ldK + koff + kc * 8;
        __builtin_amdgcn_global_load_lds((const __attribute__((address_space(1))) unsigned int*)src,
                                         (__attribute__((address_space(3))) unsigned int*)(ldsbase + chunk * 16),
                                         16, 0, 0);
    }
}

template <int K, int MODE>
__global__ __launch_bounds__(256, 3) void gemm_mfma(
    const unsigned short* __restrict__ Ah, const unsigned short* __restrict__ Al,  // [Mrows][K]
    const unsigned short* __restrict__ Bh, const unsigned short* __restrict__ Bl,  // [256][K] (transposed W)
    const float* __restrict__ bias, const float* __restrict__ addv,                // MODE1
    const float* __restrict__ scale,                                               // MODE2
    float* __restrict__ outF,                                                      // MODE0/2
    unsigned short* __restrict__ outH, unsigned short* __restrict__ outL,          // MODE1
    int Mrows, int out_base) {
    __shared__ char lds[32768];
    const int t = threadIdx.x;
    const int lane = t & 63;
    const int wid = t >> 6;
    const int wr = wid >> 1, wc = wid & 1;
    const int row0 = blockIdx.x * 128;
    const int col0 = blockIdx.y * 128;
    const int l15 = lane & 15;
    const int l4 = lane >> 4;           // kc = 16B chunk (0..3) within 32-k row

    char* ldsA = lds;
    char* ldsB = lds + 16384;

    f32x4 acc[4][4];
#pragma unroll
    for (int i = 0; i < 4; i++)
#pragma unroll
        for (int j = 0; j < 4; j++)
#pragma unroll
            for (int q = 0; q < 4; q++) acc[i][j][q] = 0.f;

    for (int ks = 0; ks < K / 32; ks++) {
        if (ks) __syncthreads();
        int koff = ks * 32;
        stage_tile32(Ah, Al, row0, Mrows - 1, K, koff, ldsA, t);
        stage_tile32(Bh, Bl, col0, 255, K, koff, ldsB, t);
        asm volatile("s_waitcnt vmcnt(0)" ::: "memory");
        __syncthreads();

        bf16x8 bh[4], bl[4];
#pragma unroll
        for (int nf = 0; nf < 4; nf++) {
            int r = wc * 64 + nf * 16 + l15;
            bh[nf] = *(const bf16x8*)(ldsB + r * 128 + ((l4 ^ (r & 7)) << 4));
            bl[nf] = *(const bf16x8*)(ldsB + r * 128 + (((4 | l4) ^ (r & 7)) << 4));
        }
#pragma unroll
        for (int mf = 0; mf < 4; mf++) {
            int r = wr * 64 + mf * 16 + l15;
            bf16x8 ah = *(const bf16x8*)(ldsA + r * 128 + ((l4 ^ (r & 7)) << 4));
            bf16x8 al = *(const bf16x8*)(ldsA + r * 128 + (((4 | l4) ^ (r & 7)) << 4));
#pragma unroll
            for (int nf = 0; nf < 4; nf++) {
                acc[mf][nf] = __builtin_amdgcn_mfma_f32_16x16x32_bf16(ah, bh[nf], acc[mf][nf], 0, 0, 0);
                acc[mf][nf] = __builtin_amdgcn_mfma_f32_16x16x32_bf16(ah, bl[nf], acc[mf][nf], 0, 0, 0);
                acc[mf][nf] = __builtin_amdgcn_mfma_f32_16x16x32_bf16(al, bh[nf], acc[mf][nf], 0, 0, 0);
            }
        }
    }

    // epilogue through LDS in two 64-row halves (32KB C-buffer)
    __syncthreads();
    float* ldsC = (float*)lds;
    const int cg = t & 31;
    const int r0 = t >> 5;
#pragma unroll
    for (int half = 0; half < 2; half++) {
        if (wr == half) {
#pragma unroll
            for (int mf = 0; mf < 4; mf++)
#pragma unroll
                for (int nf = 0; nf < 4; nf++) {
                    int lr = mf * 16 + l4 * 4;
                    int c = wc * 64 + nf * 16 + l15;
#pragma unroll
                    for (int q = 0; q < 4; q++) ldsC[(lr + q) * 128 + c] = acc[mf][nf][q];
                }
        }
        __syncthreads();
#pragma unroll
        for (int i = 0; i < 8; i++) {
            int lr = r0 + i * 8;
            int grow = row0 + half * 64 + lr;
            if (grow >= Mrows) continue;
            f32x4 v = *(const f32x4*)&ldsC[lr * 128 + cg * 4];
            int gc = col0 + cg * 4;
            if (MODE == 1) {
                f32x4 bv = *(const f32x4*)(bias + gc);
                f32x4 av = *(const f32x4*)(addv + (size_t)grow * 256 + gc);
                v += bv + av;
            } else if (MODE == 2) {
                v *= scale[grow];
            }
            size_t ob = (size_t)(out_base + grow) * 256 + gc;
            if (MODE == 1) {
                u16x4 hv, lv;
#pragma unroll
                for (int j = 0; j < 4; j++) {
                    unsigned short h = f2bf(v[j]);
                    hv[j] = h;
                    lv[j] = f2bf(v[j] - bf2f(h));
                }
                *(u16x4*)(outH + ob) = hv;
                *(u16x4*)(outL + ob) = lv;
            } else {
                *(f32x4*)(outF + ob) = v;
            }
        }
        __syncthreads();
    }
}

// ---------------------------------------------------------------------------
// GCN aggregation, f32 gather: one wave per node, lane = 4 cols (16B loads),
// unrolled x4.  Outputs stored NON-TEMPORAL so the 153MB of x-plane writes
// don't evict g from L3 (g fits L3; gather re-reads should hit L3).
// ---------------------------------------------------------------------------
__global__ __launch_bounds__(256) void gcn_aggregate_f32(
    const float* __restrict__ g, const int* __restrict__ offs, const int* __restrict__ adj,
    const float* __restrict__ dinv, const float* __restrict__ bias,
    unsigned short* __restrict__ xh, unsigned short* __restrict__ xl, int do_relu) {
    int wave = threadIdx.x >> 6;
    int lane = threadIdx.x & 63;
    int d = blockIdx.x * 4 + wave;
    int c0 = lane * 4;

    f32x4 acc0 = *(const f32x4*)&g[(size_t)d * D + c0];   // self term
    f32x4 acc1 = {0.f, 0.f, 0.f, 0.f};
    f32x4 acc2 = {0.f, 0.f, 0.f, 0.f};
    f32x4 acc3 = {0.f, 0.f, 0.f, 0.f};
    int beg = offs[d], end = offs[d + 1];
    int i = beg;
    for (; i + 3 < end; i += 4) {
        int s0 = adj[i], s1 = adj[i + 1], s2 = adj[i + 2], s3 = adj[i + 3];
        acc0 += *(const f32x4*)&g[(size_t)s0 * D + c0];
        acc1 += *(const f32x4*)&g[(size_t)s1 * D + c0];
        acc2 += *(const f32x4*)&g[(size_t)s2 * D + c0];
        acc3 += *(const f32x4*)&g[(size_t)s3 * D + c0];
    }
    for (; i < end; ++i) {
        int s = adj[i];
        acc0 += *(const f32x4*)&g[(size_t)s * D + c0];
    }
    f32x4 acc = (acc0 + acc1) + (acc2 + acc3);

    float dv = dinv[d];
    f32x4 bv = *(const f32x4*)&bias[c0];
    union { u16x4 v; unsigned long long q; } hv, lv;
#pragma unroll
    for (int j = 0; j < 4; j++) {
        float v = fmaf(dv, acc[j], bv[j]);
        if (do_relu) v = fmaxf(v, 0.f);
        unsigned short h = f2bf(v);
        hv.v[j] = h;
        lv.v[j] = f2bf(v - bf2f(h));
    }
    size_t ob = (size_t)d * D + c0;
    __builtin_nontemporal_store(hv.q, (unsigned long long*)(xh + ob));
    __builtin_nontemporal_store(lv.q, (unsigned long long*)(xl + ob));
}

// ---------------------------------------------------------------------------
// Edge MLP: preds[e] = relu(A[u] + B[p] + m1b) . m2w + m2b (one wave per edge)
// ---------------------------------------------------------------------------
__global__ __launch_bounds__(256) void edge_mlp(
    const float* __restrict__ ab, const int* __restrict__ ei,
    const float* __restrict__ m1b, const float* __restrict__ m2w, const float* __restrict__ m2b,
    float* __restrict__ preds, int E) {
    int wave = threadIdx.x >> 6;
    int lane = threadIdx.x & 63;
    int e = blockIdx.x * 4 + wave;
    if (e >= E) return;
    int u = ei[e];
    int p = ei[E + e];
    int c0 = lane * 4;
    f32x4 au = *(const f32x4*)&ab[(size_t)u * D + c0];
    f32x4 bp = *(const f32x4*)&ab[(size_t)p * D + c0];
    f32x4 bb = *(const f32x4*)&m1b[c0];
    f32x4 w = *(const f32x4*)&m2w[c0];
    float h0 = fmaxf(au[0] + bp[0] + bb[0], 0.f);
    float h1 = fmaxf(au[1] + bp[1] + bb[1], 0.f);
    float h2 = fmaxf(au[2] + bp[2] + bb[2], 0.f);
    float h3 = fmaxf(au[3] + bp[3] + bb[3], 0.f);
    float partial = h0 * w[0] + h1 * w[1] + h2 * w[2] + h3 * w[3];
#pragma unroll
    for (int off = 32; off > 0; off >>= 1) partial += __shfl_down(partial, off);
    if (lane == 0) preds[e] = partial + m2b[0];
}

// ---------------------------------------------------------------------------
extern "C" void kernel_launch(void* const* d_in, const int* in_sizes, int n_in,
                              void* d_out, int out_size, void* d_ws, size_t ws_size,
                              hipStream_t stream) {
    const int* ei = (const int*)d_in[0];
    const float* user_feat = (const float*)d_in[1];
    const float* prod_feat = (const float*)d_in[2];
    const float* user_emb = (const float*)d_in[3];
    const float* prod_emb = (const float*)d_in[4];
    const float* uW = (const float*)d_in[5];
    const float* ub = (const float*)d_in[6];
    const float* pW = (const float*)d_in[7];
    const float* pb = (const float*)d_in[8];
    const float* c1W = (const float*)d_in[9];
    const float* c1b = (const float*)d_in[10];
    const float* c2W = (const float*)d_in[11];
    const float* c2b = (const float*)d_in[12];
    const float* m1W = (const float*)d_in[13];
    const float* m1b = (const float*)d_in[14];
    const float* m2w = (const float*)d_in[15];
    const float* m2b = (const float*)d_in[16];
    float* preds = (float*)d_out;

    uint8_t* ws = (uint8_t*)d_ws;
    size_t off = 0;
    auto alloc = [&](size_t bytes) {
        size_t o = off;
        off = (off + bytes + 255) & ~(size_t)255;
        return o;
    };
    const size_t NROW = (size_t)N_NODES * D;   // 38.4M elems
    unsigned short* xh = (unsigned short*)(ws + alloc(NROW * 2));
    unsigned short* xl = (unsigned short*)(ws + alloc(NROW * 2));
    uint8_t* Greg = ws + alloc(NROW * 4);      // union: g f32 | ab f32 | feature planes
    float* gF = (float*)Greg;
    float* ab = (float*)Greg;
    unsigned short* ufh = (unsigned short*)Greg;
    unsigned short* ufl = ufh + (size_t)NUM_USERS * 128;
    unsigned short* pfh = ufl + (size_t)NUM_USERS * 128;
    unsigned short* pfl = pfh + (size_t)NUM_PRODUCTS * 128;

    unsigned short* uWth = (unsigned short*)(ws + alloc(256 * 128 * 2));
    unsigned short* uWtl = (unsigned short*)(ws + alloc(256 * 128 * 2));
    unsigned short* pWth = (unsigned short*)(ws + alloc(256 * 128 * 2));
    unsigned short* pWtl = (unsigned short*)(ws + alloc(256 * 128 * 2));
    unsigned short* c1h = (unsigned short*)(ws + alloc(256 * 256 * 2));
    unsigned short* c1l = (unsigned short*)(ws + alloc(256 * 256 * 2));
    unsigned short* c2h = (unsigned short*)(ws + alloc(256 * 256 * 2));
    unsigned short* c2l = (unsigned short*)(ws + alloc(256 * 256 * 2));
    unsigned short* m1th = (unsigned short*)(ws + alloc(256 * 256 * 2));
    unsigned short* m1tl = (unsigned short*)(ws + alloc(256 * 256 * 2));
    unsigned short* m1bh = (unsigned short*)(ws + alloc(256 * 256 * 2));
    unsigned short* m1bl = (unsigned short*)(ws + alloc(256 * 256 * 2));

    float* dinv = (float*)(ws + alloc((size_t)N_NODES * 4));
    int* cnt = (int*)(ws + alloc((size_t)N_NODES * 4));
    int* cursor = (int*)(ws + alloc((size_t)N_NODES * 4));
    int* offs = (int*)(ws + alloc((size_t)(N_NODES + 1) * 4));
    int* adj = (int*)(ws + alloc((size_t)2 * NUM_EDGES * 4));
    int* bsum = (int*)(ws + alloc(4096));
    int* bscan = (int*)(ws + alloc(4096));

    const int NB = (N_NODES + SCAN_CHUNK - 1) / SCAN_CHUNK;

    hipMemsetAsync(cnt, 0, (size_t)N_NODES * 4, stream);
    hipMemsetAsync(cursor, 0, (size_t)N_NODES * 4, stream);

    // CSR + norm
    count_deg<<<(NUM_EDGES + 255) / 256, 256, 0, stream>>>(ei, cnt, NUM_EDGES);
    compute_dinv<<<(N_NODES + 255) / 256, 256, 0, stream>>>(cnt, dinv, N_NODES);
    scan_partials<<<NB, 256, 0, stream>>>(cnt, bsum, N_NODES);
    scan_bsums<<<1, 256, 0, stream>>>(bsum, bscan, NB, offs, N_NODES);
    scan_final<<<NB, 256, 0, stream>>>(cnt, bscan, offs, N_NODES);
    fill_adj<<<(NUM_EDGES + 255) / 256, 256, 0, stream>>>(ei, offs, cursor, adj, NUM_EDGES);

    // weight transpose+split
    convW<<<128, 256, 0, stream>>>(uW, uWth, uWtl, 128);
    convW<<<128, 256, 0, stream>>>(pW, pWth, pWtl, 128);
    convW<<<256, 256, 0, stream>>>(c1W, c1h, c1l, 256);
    convW<<<256, 256, 0, stream>>>(c2W, c2h, c2l, 256);
    convW<<<256, 256, 0, stream>>>(m1W, m1th, m1tl, 256);
    convW<<<256, 256, 0, stream>>>(m1W + 256 * 256, m1bh, m1bl, 256);

    // feature split (into G region; free until conv1 output)
    splitF<<<(NUM_USERS * 128 / 4 + 255) / 256, 256, 0, stream>>>(user_feat, ufh, ufl, NUM_USERS * 128 / 4);
    splitF<<<(NUM_PRODUCTS * 128 / 4 + 255) / 256, 256, 0, stream>>>(prod_feat, pfh, pfl, NUM_PRODUCTS * 128 / 4);

    const int TU = (NUM_USERS + 127) / 128;      // 782
    const int TP = (NUM_PRODUCTS + 127) / 128;   // 391
    const int TN = (N_NODES + 127) / 128;        // 1172

    // input transforms: x = feat @ W + b + emb  (planes)
    gemm_mfma<128, 1><<<dim3(TU, 2), 256, 0, stream>>>(ufh, ufl, uWth, uWtl, ub, user_emb, nullptr,
                                                       nullptr, xh, xl, NUM_USERS, 0);
    gemm_mfma<128, 1><<<dim3(TP, 2), 256, 0, stream>>>(pfh, pfl, pWth, pWtl, pb, prod_emb, nullptr,
                                                       nullptr, xh, xl, NUM_PRODUCTS, NUM_USERS);

    // conv1: g = (x @ c1W) * dinv (f32) ; x = split(relu(dinv*(g[d]+sum g[s]) + c1b))
    gemm_mfma<256, 2><<<dim3(TN, 2), 256, 0, stream>>>(xh, xl, c1h, c1l, nullptr, nullptr, dinv,
                                                       gF, nullptr, nullptr, N_NODES, 0);
    gcn_aggregate_f32<<<N_NODES / 4, 256, 0, stream>>>(gF, offs, adj, dinv, c1b, xh, xl, 1);

    // conv2
    gemm_mfma<256, 2><<<dim3(TN, 2), 256, 0, stream>>>(xh, xl, c2h, c2l, nullptr, nullptr, dinv,
                                                       gF, nullptr, nullptr, N_NODES, 0);
    gcn_aggregate_f32<<<N_NODES / 4, 256, 0, stream>>>(gF, offs, adj, dinv, c2b, xh, xl, 0);

    // m1: A = user_out @ m1W_top ; B = prod_out @ m1W_bot  -> ab (f32, aliases G region)
    gemm_mfma<256, 0><<<dim3(TU, 2), 256, 0, stream>>>(xh, xl, m1th, m1tl, nullptr, nullptr, nullptr,
                                                       ab, nullptr, nullptr, NUM_USERS, 0);
    gemm_mfma<256, 0><<<dim3(TP, 2), 256, 0, stream>>>(xh + (size_t)NUM_USERS * D, xl + (size_t)NUM_USERS * D,
                                                       m1bh, m1bl, nullptr, nullptr, nullptr,
                                                       ab, nullptr, nullptr, NUM_PRODUCTS, NUM_USERS);

    // preds
    edge_mlp<<<NUM_EDGES / 4, 256, 0, stream>>>(ab, ei, m1b, m2w, m2b, preds, NUM_EDGES);
}